// Round 8
// baseline (958.891 us; speedup 1.0000x reference)
//
#include <hip/hip_runtime.h>
#include <hip/hip_bf16.h>

#define N_NODES 50176
#define PER 392
#define E_BI (N_NODES * 4)      // 200704
#define E_KNN (N_NODES * 16)    // 802816
#define E_TOT (E_BI + E_KNN)    // 1003520
#define KN_BI (N_NODES * 5)     // 250880
#define KN_TOT (N_NODES * 14)   // 702464
#define AH_S 288                // ah row stride (shorts): [a(128) | h(128) | cnt(32)]
#define AH_U 144
#define ECAP 1536               // LDS elist staging capacity per block

typedef __attribute__((ext_vector_type(8))) short short8;
typedef __attribute__((ext_vector_type(4))) float float4v;
typedef unsigned int uint;
typedef unsigned short ushort;

__device__ __forceinline__ float sigmoidf_(float x) { return 1.f / (1.f + __expf(-x)); }
__device__ __forceinline__ ushort f2bu(float x) {
    __hip_bfloat16 t = __float2bfloat16(x);
    return *reinterpret_cast<ushort*>(&t);
}
__device__ __forceinline__ float blo(uint u) { return __uint_as_float(u << 16); }
__device__ __forceinline__ float bhi(uint u) { return __uint_as_float(u & 0xFFFF0000u); }

// ================= fused aggregate + per-etype transform (v5) =================
// Block = 16 node rows, 512 threads: 32 threads/row (4 ch each) -> 2 rows/wave
// (low divergence), 8 waves x 16 out-cols MFMA. elist + indptr staged in LDS.
template<int NET>
__global__ __launch_bounds__(512) void msg_kernel(
    const uint* __restrict__ hb,           // [N][64] uints (h bf16 packed)
    const int* __restrict__ indptr,        // [N*NET+1] slice (absolute into elist)
    const int* __restrict__ elist,
    const ushort* __restrict__ Bfrag,      // fragment-ordered weights
    ushort* __restrict__ aout)             // ah base; write cols 0..127, stride AH_S
{
    __shared__ ushort As[4][16][40];       // 5.1 KB A tile, chunk-major, 80B rows
    __shared__ int sIp[16 * NET + 1];
    __shared__ int sE[ECAP];
    const int tid = threadIdx.x;
    const int bm = blockIdx.x * 16;
    const int wave = tid >> 6, lane = tid & 63;
    const int quad = lane >> 4, lrow = lane & 15;
    const int r = tid >> 5;                // node row 0..15
    const int sub = tid & 31;              // 4-ch group
    uint* AsU = (uint*)As;                 // [ch][16][20] uints

    for (int i = tid; i <= 16 * NET; i += 512) sIp[i] = indptr[bm * NET + i];
    __syncthreads();
    const int e0 = sIp[0];
    const int ecnt = sIp[16 * NET] - e0;
    const bool staged = (ecnt <= ECAP);
    if (staged) {
        for (int i = tid; i < ecnt; i += 512) sE[i] = elist[e0 + i];
    }
    __syncthreads();

    float4v acc = {};

    for (int et = 0; et < NET; et++) {
        const int beg = sIp[r * NET + et], end = sIp[r * NET + et + 1];
        float av0 = 0.f, av1 = 0.f, av2 = 0.f, av3 = 0.f;
        for (int j = beg; j < end; j++) {
            int src = staged ? sE[j - e0] : elist[j];
            uint2 u = *(const uint2*)(hb + (size_t)src * 64 + sub * 2);
            av0 += blo(u.x); av1 += bhi(u.x);
            av2 += blo(u.y); av3 += bhi(u.y);
        }
        __syncthreads();                   // protect As from previous MFMA reads
        {
            int ch = sub >> 3;
            int p = (ch * 16 + r) * 20 + (sub & 7) * 2;
            AsU[p]     = (uint)f2bu(av0) | ((uint)f2bu(av1) << 16);
            AsU[p + 1] = (uint)f2bu(av2) | ((uint)f2bu(av3) << 16);
        }
        __syncthreads();
#pragma unroll
        for (int ch = 0; ch < 4; ch++) {
            short8 af = *(const short8*)&As[ch][lrow][quad * 8];
            short8 bfr = *(const short8*)(Bfrag +
                ((size_t)((et * 4 + ch) * 8 + wave) << 9) + lane * 8);
            acc = __builtin_amdgcn_mfma_f32_16x16x32_bf16(af, bfr, acc, 0, 0, 0);
        }
    }

    // epilogue: C layout col=lane&15, row=quad*4+reg ; wave covers cols [wave*16, +16)
#pragma unroll
    for (int rr = 0; rr < 4; rr++) {
        size_t row = (size_t)(bm + quad * 4 + rr);
        aout[row * AH_S + wave * 16 + lrow] = f2bu(acc[rr]);
    }
}

// ================= bf16 MFMA GEMM (GRU / readout) =================
__global__ __launch_bounds__(256) void mgemm_kernel(
    const __hip_bfloat16* __restrict__ A, int lda,
    const __hip_bfloat16* __restrict__ Bt, int ldb,
    const float* __restrict__ bias,
    void* __restrict__ C, int ldc, int K,
    int out_bf16, int accum)
{
    __shared__ short As[128 * 32];
    __shared__ short Bs[128 * 32];
    const int tid = threadIdx.x;
    const int bm = blockIdx.x * 128;
    const int bn = blockIdx.y * 128;
    const int wave = tid >> 6, lane = tid & 63;
    const int quad = lane >> 4, lrow = lane & 15;
    const int wr = wave & 1, wc = wave >> 1;

    const short* Ap = (const short*)A;
    const short* Bp = (const short*)Bt;

    float4v acc[4][4] = {};

    for (int k0 = 0; k0 < K; k0 += 32) {
        __syncthreads();
#pragma unroll
        for (int p = 0; p < 2; p++) {
            int lin = p * 256 + tid;
            int r = lin >> 2;
            int kc = (lin & 3) * 8;
            *(short8*)&As[r * 32 + kc] = *(const short8*)(Ap + (size_t)(bm + r) * lda + k0 + kc);
            *(short8*)&Bs[r * 32 + kc] = *(const short8*)(Bp + (size_t)(bn + r) * ldb + k0 + kc);
        }
        __syncthreads();
        short8 af[4], bfr[4];
#pragma unroll
        for (int i = 0; i < 4; i++)
            af[i] = *(const short8*)&As[(wr * 64 + i * 16 + lrow) * 32 + quad * 8];
#pragma unroll
        for (int j = 0; j < 4; j++)
            bfr[j] = *(const short8*)&Bs[(wc * 64 + j * 16 + lrow) * 32 + quad * 8];
#pragma unroll
        for (int i = 0; i < 4; i++)
#pragma unroll
            for (int j = 0; j < 4; j++)
                acc[i][j] = __builtin_amdgcn_mfma_f32_16x16x32_bf16(af[i], bfr[j], acc[i][j], 0, 0, 0);
    }

#pragma unroll
    for (int i = 0; i < 4; i++) {
#pragma unroll
        for (int j = 0; j < 4; j++) {
            int col = bn + wc * 64 + j * 16 + lrow;
            float bv = bias ? bias[col] : 0.f;
#pragma unroll
            for (int r = 0; r < 4; r++) {
                size_t row = (size_t)(bm + wr * 64 + i * 16 + quad * 4 + r);
                float v = acc[i][j][r] + bv;
                if (out_bf16) {
                    ((__hip_bfloat16*)C)[row * ldc + col] = __float2bfloat16(v);
                } else {
                    float* cp = (float*)C + row * ldc + col;
                    if (accum) *cp += v;
                    else       *cp = v;
                }
            }
        }
    }
}

static inline void mgemm(hipStream_t st, const __hip_bfloat16* A, int lda,
                         const __hip_bfloat16* Bt, int ldb, const float* bias,
                         void* C, int ldc, int M, int Ncols, int K,
                         int out_bf16, int accum)
{
    dim3 grid(M / 128, Ncols / 128);
    mgemm_kernel<<<grid, 256, 0, st>>>(A, lda, Bt, ldb, bias, C, ldc, K, out_bf16, accum);
}

// ================= small fp32 GEMM (stage-3 MLP only) =================
__global__ __launch_bounds__(256) void gemm_kernel(
    const float* __restrict__ A, int lda,
    const float* __restrict__ B, int ldb,
    const float* __restrict__ bias,
    float* __restrict__ C, int ldc,
    int K, int act)
{
    __shared__ float As[32][68];
    __shared__ float Bs[32][68];
    const int tid = threadIdx.x;
    const int bm = blockIdx.x * 64;
    const int bn = blockIdx.y * 64;
    const int tm = (tid & 15) * 4;
    const int tn = (tid >> 4) * 4;
    float acc[4][4] = {};

    for (int k0 = 0; k0 < K; k0 += 32) {
#pragma unroll
        for (int p = 0; p < 2; p++) {
            int lin = p * 256 + tid;
            int ar = lin >> 3;
            int ac = (lin & 7) << 2;
            float4 av = *(const float4*)(A + (size_t)(bm + ar) * lda + (k0 + ac));
            As[ac + 0][ar] = av.x;
            As[ac + 1][ar] = av.y;
            As[ac + 2][ar] = av.z;
            As[ac + 3][ar] = av.w;
            int br = lin >> 4;
            int bc = (lin & 15) << 2;
            *(float4*)&Bs[br][bc] = *(const float4*)(B + (size_t)(k0 + br) * ldb + (bn + bc));
        }
        __syncthreads();
#pragma unroll
        for (int k = 0; k < 32; k++) {
            float4 a4 = *(const float4*)&As[k][tm];
            float4 b4 = *(const float4*)&Bs[k][tn];
            float av[4] = {a4.x, a4.y, a4.z, a4.w};
            float bv[4] = {b4.x, b4.y, b4.z, b4.w};
#pragma unroll
            for (int i = 0; i < 4; i++)
#pragma unroll
                for (int j = 0; j < 4; j++)
                    acc[i][j] += av[i] * bv[j];
        }
        __syncthreads();
    }
#pragma unroll
    for (int i = 0; i < 4; i++) {
        size_t row = (size_t)(bm + tm + i);
#pragma unroll
        for (int j = 0; j < 4; j++) {
            int col = bn + tn + j;
            float val = acc[i][j] + (bias ? bias[col] : 0.f);
            if (act == 1) val = fmaxf(val, 0.f);
            C[row * ldc + col] = val;
        }
    }
}

// ================= weight prep =================
// Bfrag[((et*4+ch)*8 + w)][lane][m] = W[et][k][c], k=ch*32+quad*8+m, c=w*16+lrow
__global__ void prep_bfrag_kernel(const float* __restrict__ W, __hip_bfloat16* __restrict__ Bf,
                                  int net)
{
    int idx = blockIdx.x * blockDim.x + threadIdx.x;   // net*16384
    int m = idx & 7;
    int lane = (idx >> 3) & 63;
    int f = idx >> 9;
    int wv = f & 7; f >>= 3;
    int ch = f & 3;
    int et = f >> 2;
    int quad = lane >> 4, lrow = lane & 15;
    int k = ch * 32 + quad * 8 + m;
    int c = wv * 16 + lrow;
    Bf[idx] = __float2bfloat16(W[et * 16384 + k * 128 + c]);
}

// GRU fused weights: Bt[512 cols][288 rows]; rows 0..127 a, 128..255 h, 256+: b@wih (cnt cols)
__global__ void prep_gru_kernel(const float* __restrict__ wih, const float* __restrict__ whh,
                                const float* __restrict__ bih, const float* __restrict__ bhh,
                                const float* __restrict__ b, int net,
                                __hip_bfloat16* __restrict__ Bt, float* __restrict__ bias)
{
    int idx = blockIdx.x * blockDim.x + threadIdx.x;   // 512*288
    int n = idx / 288;
    int k = idx - n * 288;
    float val = 0.f;
    if (k < 128) {
        val = (n < 384) ? wih[k * 384 + n] : 0.f;
    } else if (k < 256) {
        int kk = k - 128;
        if (n < 256)       val = whh[kk * 384 + n];
        else if (n >= 384) val = whh[kk * 384 + (n - 128)];
    } else {
        int j = k - 256;
        if (j < net && n < 384) {
            float s = 0.f;
            for (int kk = 0; kk < 128; kk++) s += b[j * 128 + kk] * wih[kk * 384 + n];
            val = s;
        }
    }
    Bt[idx] = __float2bfloat16(val);
    if (k == 0) bias[n] = (n < 256) ? bih[n] + bhh[n] : (n < 384 ? bih[n] : bhh[n - 128]);
}

__global__ void prep_ro1_kernel(const float* __restrict__ iw, const float* __restrict__ jw,
                                const float* __restrict__ ib, const float* __restrict__ jb,
                                __hip_bfloat16* __restrict__ Bt, float* __restrict__ bias)
{
    int idx = blockIdx.x * blockDim.x + threadIdx.x;   // 32768
    int n = idx >> 7;
    int k = idx & 127;
    float val = (n < 128) ? iw[k * 128 + n] : jw[k * 128 + (n - 128)];
    Bt[idx] = __float2bfloat16(val);
    if (k == 0) bias[n] = (n < 128) ? ib[n] : jb[n - 128];
}

__global__ void prep_ro2_kernel(const float* __restrict__ iw, __hip_bfloat16* __restrict__ Bt,
                                int Fin)
{
    int idx = blockIdx.x * blockDim.x + threadIdx.x;   // 128*Fin
    int n = idx / Fin;
    int k = idx - n * Fin;
    Bt[idx] = __float2bfloat16(iw[(128 + k) * 128 + n]);
}

__global__ void f2b_kernel(const float* __restrict__ f, __hip_bfloat16* __restrict__ b)
{
    int idx = blockIdx.x * blockDim.x + threadIdx.x;
    b[idx] = __float2bfloat16(f[idx]);
}

// ================= merged CSR build (both graphs, concatenated keyspace) =================
__global__ void hist2_kernel(const int* __restrict__ bd, const int* __restrict__ be,
                             const int* __restrict__ kd, const int* __restrict__ ke,
                             int* __restrict__ counts)
{
    int e = blockIdx.x * blockDim.x + threadIdx.x;
    if (e >= E_TOT) return;
    if (e < E_BI) atomicAdd(&counts[bd[e] * 5 + be[e]], 1);
    else { int i = e - E_BI; atomicAdd(&counts[KN_BI + kd[i] * 9 + ke[i]], 1); }
}

__global__ void scan1_kernel(const int* __restrict__ counts, int* __restrict__ local_ex,
                             int* __restrict__ partial)
{
    __shared__ int s[256];
    int t = threadIdx.x;
    int i = blockIdx.x * 256 + t;
    int v = counts[i];
    s[t] = v;
    __syncthreads();
    for (int off = 1; off < 256; off <<= 1) {
        int x = 0;
        if (t >= off) x = s[t - off];
        __syncthreads();
        if (t >= off) s[t] += x;
        __syncthreads();
    }
    local_ex[i] = s[t] - v;
    if (t == 255) partial[blockIdx.x] = s[255];
}

__global__ void scan2b_kernel(int* __restrict__ partial, int nb, int* __restrict__ last, int E)
{
    __shared__ int s[256];
    int t = threadIdx.x;
    int loc[11];
    int sum = 0;
#pragma unroll
    for (int q = 0; q < 11; q++) {
        int idx = t * 11 + q;
        int v = (idx < nb) ? partial[idx] : 0;
        loc[q] = sum; sum += v;
    }
    s[t] = sum;
    __syncthreads();
    for (int off = 1; off < 256; off <<= 1) {
        int x = 0;
        if (t >= off) x = s[t - off];
        __syncthreads();
        if (t >= off) s[t] += x;
        __syncthreads();
    }
    int excl = s[t] - sum;
#pragma unroll
    for (int q = 0; q < 11; q++) {
        int idx = t * 11 + q;
        if (idx < nb) partial[idx] = excl + loc[q];
    }
    if (t == 0) *last = E;
}

__global__ void scan3c_kernel(int* __restrict__ indptr, const int* __restrict__ partial,
                              int* __restrict__ cursor)
{
    int i = blockIdx.x * 256 + threadIdx.x;
    int v = indptr[i] + partial[blockIdx.x];
    indptr[i] = v;
    cursor[i] = v;
}

__global__ void fill2_kernel(const int* __restrict__ bs, const int* __restrict__ bd,
                             const int* __restrict__ be,
                             const int* __restrict__ ks, const int* __restrict__ kd,
                             const int* __restrict__ ke,
                             int* __restrict__ cursor, int* __restrict__ elist)
{
    int e = blockIdx.x * blockDim.x + threadIdx.x;
    if (e >= E_TOT) return;
    if (e < E_BI) {
        int pos = atomicAdd(&cursor[bd[e] * 5 + be[e]], 1);
        elist[pos] = bs[e];
    } else {
        int i = e - E_BI;
        int pos = atomicAdd(&cursor[KN_BI + kd[i] * 9 + ke[i]], 1);
        elist[pos] = ks[i];
    }
}

// cnt columns of ah
__global__ void cnt_kernel(const int* __restrict__ indptr, int net, ushort* __restrict__ ah)
{
    int idx = blockIdx.x * blockDim.x + threadIdx.x;   // N*32
    int v = idx >> 5;
    int j = idx & 31;
    float cv = 0.f;
    if (j < net) cv = (float)(indptr[v * net + j + 1] - indptr[v * net + j]);
    ah[(size_t)v * AH_S + 256 + j] = f2bu(cv);
}

// ================= elementwise =================
__global__ void pad_kernel(const float* __restrict__ fsrc, const ushort* __restrict__ bsrc,
                           float* __restrict__ h, uint* __restrict__ ahp,
                           uint* __restrict__ hb, int Fin)
{
    int idx = blockIdx.x * blockDim.x + threadIdx.x;   // N*32
    int v = idx >> 5;
    int c = (idx & 31) * 4;
    float4 val = make_float4(0.f, 0.f, 0.f, 0.f);
    if (bsrc) {
        uint2 u = *(const uint2*)(bsrc + (size_t)v * Fin + c);
        val.x = blo(u.x); val.y = bhi(u.x);
        val.z = blo(u.y); val.w = bhi(u.y);
    } else if (c < Fin) {
        val = *(const float4*)(fsrc + (size_t)v * Fin + c);
    }
    *(float4*)(h + (size_t)v * 128 + c) = val;
    uint2 pk;
    pk.x = (uint)f2bu(val.x) | ((uint)f2bu(val.y) << 16);
    pk.y = (uint)f2bu(val.z) | ((uint)f2bu(val.w) << 16);
    *(uint2*)(ahp + (size_t)v * AH_U + 64 + c / 2) = pk;
    *(uint2*)(hb + (size_t)v * 64 + c / 2) = pk;
}

__global__ void gru_gate_kernel(const ushort* __restrict__ rzin, float* __restrict__ h,
                                uint* __restrict__ ahp, uint* __restrict__ hb)
{
    int idx = blockIdx.x * blockDim.x + threadIdx.x;   // N*32
    int v = idx >> 5;
    int c = (idx & 31) * 4;
    const ushort* base = rzin + (size_t)v * 512;
    uint2 ru = *(const uint2*)(base + c);
    uint2 zu = *(const uint2*)(base + 128 + c);
    uint2 iu = *(const uint2*)(base + 256 + c);
    uint2 nu = *(const uint2*)(base + 384 + c);
    float4 h4 = *(const float4*)(h + (size_t)v * 128 + c);
    float4 o;
    {
        float r = sigmoidf_(blo(ru.x)), z = sigmoidf_(blo(zu.x));
        o.x = (1.f - z) * tanhf(blo(iu.x) + r * blo(nu.x)) + z * h4.x;
        r = sigmoidf_(bhi(ru.x)); z = sigmoidf_(bhi(zu.x));
        o.y = (1.f - z) * tanhf(bhi(iu.x) + r * bhi(nu.x)) + z * h4.y;
        r = sigmoidf_(blo(ru.y)); z = sigmoidf_(blo(zu.y));
        o.z = (1.f - z) * tanhf(blo(iu.y) + r * blo(nu.y)) + z * h4.z;
        r = sigmoidf_(bhi(ru.y)); z = sigmoidf_(bhi(zu.y));
        o.w = (1.f - z) * tanhf(bhi(iu.y) + r * bhi(nu.y)) + z * h4.w;
    }
    *(float4*)(h + (size_t)v * 128 + c) = o;
    uint2 pk;
    pk.x = (uint)f2bu(o.x) | ((uint)f2bu(o.y) << 16);
    pk.y = (uint)f2bu(o.z) | ((uint)f2bu(o.w) << 16);
    *(uint2*)(ahp + (size_t)v * AH_U + 64 + c / 2) = pk;
    *(uint2*)(hb + (size_t)v * 64 + c / 2) = pk;
}

__global__ void sigmul_kernel(const float* __restrict__ uv, float* __restrict__ o,
                              uint* __restrict__ obp)
{
    int idx = blockIdx.x * blockDim.x + threadIdx.x;   // N*32
    int v = idx >> 5;
    int c = (idx & 31) * 4;
    float4 u4 = *(const float4*)(uv + (size_t)v * 256 + c);
    float4 v4 = *(const float4*)(uv + (size_t)v * 256 + 128 + c);
    float4 r;
    r.x = sigmoidf_(u4.x) * v4.x;
    r.y = sigmoidf_(u4.y) * v4.y;
    r.z = sigmoidf_(u4.z) * v4.z;
    r.w = sigmoidf_(u4.w) * v4.w;
    if (o) *(float4*)(o + (size_t)v * 128 + c) = r;
    if (obp) {
        uint2 pk;
        pk.x = (uint)f2bu(r.x) | ((uint)f2bu(r.y) << 16);
        pk.y = (uint)f2bu(r.z) | ((uint)f2bu(r.w) << 16);
        *(uint2*)(obp + (size_t)v * 64 + c / 2) = pk;
    }
}

__global__ void pool_kernel(const float* __restrict__ r2, float* __restrict__ pooled)
{
    int s = blockIdx.x;
    int c = threadIdx.x;
    const float* base = r2 + (size_t)(2 * s) * PER * 128;
    float acc = 0.f;
    for (int i = 0; i < PER; i++) acc += base[(size_t)i * 128 + c];
    pooled[s * 128 + c] = acc;
}

__global__ void out_kernel(const float* __restrict__ x2, const float* __restrict__ wo,
                           const float* __restrict__ bo, float* __restrict__ out)
{
    int row = blockIdx.x;
    int t = threadIdx.x;
    float s = x2[row * 128 + t] * wo[t] + x2[row * 128 + 64 + t] * wo[64 + t];
#pragma unroll
    for (int off = 32; off; off >>= 1) s += __shfl_down(s, off);
    if (t == 0) out[row] = s + bo[0];
}

struct GGParams {
    const float *W, *b, *wih, *whh, *bih, *bhh, *iw, *ib, *jw, *jb;
};

struct WsPtrs {
    float* h;
    __hip_bfloat16* ah;       // [N,288] bf16
    float* G;                 // 4*n128 floats: rzin(bf16) / uv / rout2 / hb
    uint* hb;                 // compact h bf16 [N][64] uints
    __hip_bfloat16* r1b;
    __hip_bfloat16* featb;
    __hip_bfloat16 *bfragB, *gruB, *ro1B, *ro2B;
    float *gruBias, *ro1Bias;
    int *indptr, *cursor, *partial, *elist;
    float *pooled, *x1, *x2;
};

template<int NET>
static void run_stage(hipStream_t st, const float* featF, const __hip_bfloat16* featB, int Fin,
                      const GGParams& p, const WsPtrs& w, const int* indptr_slice,
                      float* rout, __hip_bfloat16* rout_b)
{
    const int N = N_NODES;
    ushort* rzin = (ushort*)w.G;            // [N,512] bf16
    float* uv    = w.G;                     // [N,256] fp32 (rzin dead)
    uint* ahp = (uint*)w.ah;

    prep_bfrag_kernel<<<(NET * 16384) / 256, 256, 0, st>>>(p.W, w.bfragB, NET);
    prep_gru_kernel<<<(512 * 288) / 256, 256, 0, st>>>(p.wih, p.whh, p.bih, p.bhh, p.b, NET,
                                                       w.gruB, w.gruBias);
    prep_ro1_kernel<<<32768 / 256, 256, 0, st>>>(p.iw, p.jw, p.ib, p.jb, w.ro1B, w.ro1Bias);
    prep_ro2_kernel<<<(128 * Fin) / 256, 256, 0, st>>>(p.iw, w.ro2B, Fin);

    cnt_kernel<<<(N * 32) / 256, 256, 0, st>>>(indptr_slice, NET, (ushort*)w.ah);
    pad_kernel<<<(N * 32) / 256, 256, 0, st>>>(featF, (const ushort*)featB, w.h, ahp, w.hb, Fin);

    for (int step = 0; step < 2; step++) {
        msg_kernel<NET><<<N / 16, 512, 0, st>>>(w.hb, indptr_slice, w.elist,
                                                (ushort*)w.bfragB, (ushort*)w.ah);
        // rz|in|hn = [a, h, cnt] @ gruB + bias -> bf16 rzin
        mgemm(st, w.ah, AH_S, w.gruB, 288, w.gruBias, rzin, 512, N, 512, 288, 1, 0);
        gru_gate_kernel<<<(N * 32) / 256, 256, 0, st>>>(rzin, w.h, ahp, w.hb);
    }

    // readout: uv = [ h@iwh + feat@iwf + ib | h@jw + jb ]
    mgemm(st, w.ah + 128, AH_S, w.ro1B, 128, w.ro1Bias, uv, 256, N, 256, 128, 0, 0);
    const __hip_bfloat16* fB = featB ? featB : w.featb;
    mgemm(st, fB, Fin, w.ro2B, Fin, nullptr, uv, 256, N, 128, Fin, 0, 1);
    sigmul_kernel<<<(N * 32) / 256, 256, 0, st>>>(uv, rout, (uint*)rout_b);
}

extern "C" void kernel_launch(void* const* d_in, const int* in_sizes, int n_in,
                              void* d_out, int out_size, void* d_ws, size_t ws_size,
                              hipStream_t stream)
{
    const float* feat    = (const float*)d_in[0];
    const int*   bi_src  = (const int*)d_in[1];
    const int*   bi_dst  = (const int*)d_in[2];
    const int*   bi_et   = (const int*)d_in[3];
    const int*   knn_src = (const int*)d_in[4];
    const int*   knn_dst = (const int*)d_in[5];
    const int*   knn_et  = (const int*)d_in[6];

    GGParams s1 { (const float*)d_in[8],  (const float*)d_in[9],  (const float*)d_in[10],
                  (const float*)d_in[11], (const float*)d_in[12], (const float*)d_in[13],
                  (const float*)d_in[14], (const float*)d_in[15], (const float*)d_in[16],
                  (const float*)d_in[17] };
    GGParams s2 { (const float*)d_in[18], (const float*)d_in[19], (const float*)d_in[20],
                  (const float*)d_in[21], (const float*)d_in[22], (const float*)d_in[23],
                  (const float*)d_in[24], (const float*)d_in[25], (const float*)d_in[26],
                  (const float*)d_in[27] };
    const float* w0 = (const float*)d_in[28];
    const float* b0 = (const float*)d_in[29];
    const float* w1 = (const float*)d_in[30];
    const float* b1 = (const float*)d_in[31];
    const float* wo = (const float*)d_in[32];
    const float* bo = (const float*)d_in[33];

    const int N = N_NODES;
    const size_t n128 = (size_t)N * 128;

    float* ws = (float*)d_ws;
    WsPtrs w;
    size_t off = 0;
    w.h      = ws + off;                       off += n128;
    w.ah     = (__hip_bfloat16*)(ws + off);    off += (size_t)N * 144;
    w.G      = ws + off;                       off += 4 * n128;
    w.hb     = (uint*)(w.G + 3 * n128);        // spare quarter of G
    w.r1b    = (__hip_bfloat16*)(ws + off);    off += n128 / 2;
    w.featb  = (__hip_bfloat16*)(ws + off);    off += n128 / 4;
    w.bfragB = (__hip_bfloat16*)(ws + off);    off += 9 * 16384 / 2;
    w.gruB   = (__hip_bfloat16*)(ws + off);    off += 512 * 288 / 2;
    w.ro1B   = (__hip_bfloat16*)(ws + off);    off += 32768 / 2;
    w.ro2B   = (__hip_bfloat16*)(ws + off);    off += 16384 / 2;
    w.gruBias = ws + off;                      off += 512;
    w.ro1Bias = ws + off;                      off += 256;
    w.indptr  = (int*)(ws + off);              off += KN_TOT + 8;
    w.cursor  = (int*)(ws + off);              off += KN_TOT;
    w.partial = (int*)(ws + off);              off += 4096;
    w.elist   = (int*)(ws + off);              off += E_TOT;
    w.pooled  = ws + off;                      off += 64 * 128;
    w.x1      = ws + off;                      off += 64 * 256;
    w.x2      = ws + off;                      off += 64 * 128;

    // ---- merged CSR build ----
    hipMemsetAsync(w.cursor, 0, KN_TOT * sizeof(int), stream);
    hist2_kernel<<<(E_TOT + 255) / 256, 256, 0, stream>>>(bi_dst, bi_et, knn_dst, knn_et, w.cursor);
    scan1_kernel<<<KN_TOT / 256, 256, 0, stream>>>(w.cursor, w.indptr, w.partial);
    scan2b_kernel<<<1, 256, 0, stream>>>(w.partial, KN_TOT / 256, w.indptr + KN_TOT, E_TOT);
    scan3c_kernel<<<KN_TOT / 256, 256, 0, stream>>>(w.indptr, w.partial, w.cursor);
    fill2_kernel<<<(E_TOT + 255) / 256, 256, 0, stream>>>(bi_src, bi_dst, bi_et,
                                                          knn_src, knn_dst, knn_et,
                                                          w.cursor, w.elist);

    f2b_kernel<<<(N * 64) / 256, 256, 0, stream>>>(feat, w.featb);

    // Stage 1: bond graph (5 etypes), Fin=64
    run_stage<5>(stream, feat, nullptr, 64, s1, w, w.indptr, nullptr, w.r1b);
    // Stage 2: knn graph (9 etypes), feat = stage-1 readout (bf16)
    float* rout2 = w.G + 2 * n128;
    run_stage<9>(stream, nullptr, w.r1b, 128, s2, w, w.indptr + KN_BI, rout2, nullptr);

    // Stage 3: ligand pooling + MLP
    pool_kernel<<<64, 128, 0, stream>>>(rout2, w.pooled);
    {
        dim3 g1(1, 4);
        gemm_kernel<<<g1, 256, 0, stream>>>(w.pooled, 128, w0, 256, b0, w.x1, 256, 128, 1);
        dim3 g2(1, 2);
        gemm_kernel<<<g2, 256, 0, stream>>>(w.x1, 256, w1, 128, b1, w.x2, 128, 256, 1);
    }
    out_kernel<<<64, 64, 0, stream>>>(w.x2, wo, bo, (float*)d_out);
}

// Round 10
// 777.535 us; speedup vs baseline: 1.2332x; 1.2332x over previous
//
#include <hip/hip_runtime.h>
#include <hip/hip_bf16.h>

#define N_NODES 50176
#define PER 392
#define E_BI (N_NODES * 4)      // 200704
#define E_KNN (N_NODES * 16)    // 802816
#define E_TOT (E_BI + E_KNN)    // 1003520
#define KN_BI (N_NODES * 5)     // 250880
#define KN_TOT (N_NODES * 14)   // 702464
#define AH_S 416                // ah row stride (shorts): [a(128)|h(128)|cnt(32)|feat(128)]
#define AH_U 208                // ... in uints

typedef __attribute__((ext_vector_type(8))) short short8;
typedef __attribute__((ext_vector_type(4))) float float4v;
typedef unsigned int uint;
typedef unsigned short ushort;

__device__ __forceinline__ float sigmoidf_(float x) { return 1.f / (1.f + __expf(-x)); }
__device__ __forceinline__ ushort f2bu(float x) {
    __hip_bfloat16 t = __float2bfloat16(x);
    return *reinterpret_cast<ushort*>(&t);
}
__device__ __forceinline__ float blo(uint u) { return __uint_as_float(u << 16); }
__device__ __forceinline__ float bhi(uint u) { return __uint_as_float(u & 0xFFFF0000u); }

// ================= fused aggregate + per-etype transform (v4 — best measured) =========
// Block = 32 node rows, 256 threads: 8 threads/row (16 ch each, 2x16B loads/edge).
template<int NET>
__global__ __launch_bounds__(256) void msg_kernel(
    const uint* __restrict__ hb,           // [N][64] uints (h bf16 packed)
    const int* __restrict__ indptr,        // [N*NET+1] slice (absolute into elist)
    const int* __restrict__ elist,
    const ushort* __restrict__ Bfrag,      // fragment-ordered weights
    ushort* __restrict__ aout)             // target ah buffer; write cols 0..127
{
    __shared__ ushort As[4][32][40];       // 10.25 KB, chunk-major, 80B rows
    const int tid = threadIdx.x;
    const int bm = blockIdx.x * 32;
    const int wave = tid >> 6, lane = tid & 63;
    const int quad = lane >> 4, lrow = lane & 15;
    const int wr = wave & 1, wc = wave >> 1;
    const int r = tid >> 3;                // node row 0..31
    const int oct = tid & 7;               // 16-ch group
    const int v = bm + r;

    uint* AsU = (uint*)As;                 // [ch][r][20] uints

    float4v acc[4] = {};

    for (int et = 0; et < NET; et++) {
        const int beg = indptr[v * NET + et], end = indptr[v * NET + et + 1];
        float av[16];
#pragma unroll
        for (int i = 0; i < 16; i++) av[i] = 0.f;

        for (int j = beg; j < end; j++) {
            int src = elist[j];
            const uint4* hp = (const uint4*)(hb + (size_t)src * 64 + oct * 8);
            uint4 u0 = hp[0];
            uint4 u1 = hp[1];
            av[0] += blo(u0.x); av[1] += bhi(u0.x);
            av[2] += blo(u0.y); av[3] += bhi(u0.y);
            av[4] += blo(u0.z); av[5] += bhi(u0.z);
            av[6] += blo(u0.w); av[7] += bhi(u0.w);
            av[8]  += blo(u1.x); av[9]  += bhi(u1.x);
            av[10] += blo(u1.y); av[11] += bhi(u1.y);
            av[12] += blo(u1.z); av[13] += bhi(u1.z);
            av[14] += blo(u1.w); av[15] += bhi(u1.w);
        }

        __syncthreads();                   // previous etype's As reads complete
        {
            int base = ((oct >> 1) * 32 + r) * 20 + (oct & 1) * 8;
#pragma unroll
            for (int u = 0; u < 8; u++)
                AsU[base + u] = (uint)f2bu(av[2 * u]) | ((uint)f2bu(av[2 * u + 1]) << 16);
        }
        __syncthreads();

#pragma unroll
        for (int ch = 0; ch < 4; ch++) {
            short8 af = *(const short8*)&As[ch][wr * 16 + lrow][quad * 8];
            const ushort* bp = Bfrag + ((size_t)(((et * 4 + ch) * 2 + wc) * 4) << 9) + lane * 8;
#pragma unroll
            for (int j = 0; j < 4; j++) {
                short8 bfr = *(const short8*)(bp + j * 512);
                acc[j] = __builtin_amdgcn_mfma_f32_16x16x32_bf16(af, bfr, acc[j], 0, 0, 0);
            }
        }
    }

#pragma unroll
    for (int j = 0; j < 4; j++) {
        int col = wc * 64 + j * 16 + lrow;
#pragma unroll
        for (int rr = 0; rr < 4; rr++) {
            size_t row = (size_t)(bm + wr * 16 + quad * 4 + rr);
            aout[row * AH_S + col] = f2bu(acc[j][rr]);
        }
    }
}

// ================= GRU GEMM with fused gate epilogue (ping-pong, race-free) ============
// Reads A = ahIn [a|h|cnt] (K=288); writes h' into ahOut h-cols (+ h fp32 + hb).
// C cols permuted: p = blk*128 + wc*64 + gate*16 + t -> gate {r,z,in,hn}, ch = blk*32+wc*16+t
__global__ __launch_bounds__(256) void gru_gemm_kernel(
    const ushort* __restrict__ A,          // ahIn base, lda AH_S
    const ushort* __restrict__ Bt,         // gruB [512][288] permuted
    const float* __restrict__ bias,        // [512] permuted
    float* __restrict__ h,
    ushort* __restrict__ ahOut, ushort* __restrict__ hbS)
{
    __shared__ ushort As[128 * 32];
    __shared__ ushort Bs[128 * 32];
    const int tid = threadIdx.x;
    const int bm = blockIdx.x * 128;
    const int bn = blockIdx.y * 128;
    const int wave = tid >> 6, lane = tid & 63;
    const int quad = lane >> 4, lrow = lane & 15;
    const int wr = wave & 1, wc = wave >> 1;

    float4v acc[4][4] = {};

    for (int k0 = 0; k0 < 288; k0 += 32) {
        __syncthreads();
#pragma unroll
        for (int p = 0; p < 2; p++) {
            int lin = p * 256 + tid;
            int r = lin >> 2;
            int kc = (lin & 3) * 8;
            *(short8*)&As[r * 32 + kc] = *(const short8*)(A + (size_t)(bm + r) * AH_S + k0 + kc);
            *(short8*)&Bs[r * 32 + kc] = *(const short8*)(Bt + (size_t)(bn + r) * 288 + k0 + kc);
        }
        __syncthreads();
        short8 af[4], bfr[4];
#pragma unroll
        for (int i = 0; i < 4; i++)
            af[i] = *(const short8*)&As[(wr * 64 + i * 16 + lrow) * 32 + quad * 8];
#pragma unroll
        for (int j = 0; j < 4; j++)
            bfr[j] = *(const short8*)&Bs[(wc * 64 + j * 16 + lrow) * 32 + quad * 8];
#pragma unroll
        for (int i = 0; i < 4; i++)
#pragma unroll
            for (int j = 0; j < 4; j++)
                acc[i][j] = __builtin_amdgcn_mfma_f32_16x16x32_bf16(af[i], bfr[j], acc[i][j], 0, 0, 0);
    }

    const int ch = (bn >> 7) * 32 + wc * 16 + lrow;
    const float b0 = bias[bn + wc * 64 + lrow];
    const float b1 = bias[bn + wc * 64 + 16 + lrow];
    const float b2 = bias[bn + wc * 64 + 32 + lrow];
    const float b3 = bias[bn + wc * 64 + 48 + lrow];
#pragma unroll
    for (int i = 0; i < 4; i++) {
#pragma unroll
        for (int r = 0; r < 4; r++) {
            size_t row = (size_t)(bm + wr * 64 + i * 16 + quad * 4 + r);
            float rr = sigmoidf_(acc[i][0][r] + b0);
            float zz = sigmoidf_(acc[i][1][r] + b1);
            float nn = tanhf(acc[i][2][r] + b2 + rr * (acc[i][3][r] + b3));
            float hold = h[row * 128 + ch];
            float hnew = (1.f - zz) * nn + zz * hold;
            h[row * 128 + ch] = hnew;
            ushort hu = f2bu(hnew);
            ahOut[row * AH_S + 128 + ch] = hu;
            hbS[row * 128 + ch] = hu;
        }
    }
}

// ================= readout GEMM with fused sigmoid-mul epilogue =================
// A = ah+128, K=288 [h|cnt|feat]; cols: p = blk*128+wc*64+j*16+t, side=j&1 (u/v),
// ch = blk*64 + wc*32 + (j>>1)*16 + t ; epilogue: rout[ch] = sigmoid(u)*v
__global__ __launch_bounds__(256) void ro_gemm_kernel(
    const ushort* __restrict__ A,
    const ushort* __restrict__ Bt,         // [256][288]
    const float* __restrict__ bias,        // [256] permuted
    float* __restrict__ rout, ushort* __restrict__ rb)
{
    __shared__ ushort As[128 * 32];
    __shared__ ushort Bs[128 * 32];
    const int tid = threadIdx.x;
    const int bm = blockIdx.x * 128;
    const int bn = blockIdx.y * 128;
    const int wave = tid >> 6, lane = tid & 63;
    const int quad = lane >> 4, lrow = lane & 15;
    const int wr = wave & 1, wc = wave >> 1;

    float4v acc[4][4] = {};

    for (int k0 = 0; k0 < 288; k0 += 32) {
        __syncthreads();
#pragma unroll
        for (int p = 0; p < 2; p++) {
            int lin = p * 256 + tid;
            int r = lin >> 2;
            int kc = (lin & 3) * 8;
            *(short8*)&As[r * 32 + kc] = *(const short8*)(A + (size_t)(bm + r) * AH_S + k0 + kc);
            *(short8*)&Bs[r * 32 + kc] = *(const short8*)(Bt + (size_t)(bn + r) * 288 + k0 + kc);
        }
        __syncthreads();
        short8 af[4], bfr[4];
#pragma unroll
        for (int i = 0; i < 4; i++)
            af[i] = *(const short8*)&As[(wr * 64 + i * 16 + lrow) * 32 + quad * 8];
#pragma unroll
        for (int j = 0; j < 4; j++)
            bfr[j] = *(const short8*)&Bs[(wc * 64 + j * 16 + lrow) * 32 + quad * 8];
#pragma unroll
        for (int i = 0; i < 4; i++)
#pragma unroll
            for (int j = 0; j < 4; j++)
                acc[i][j] = __builtin_amdgcn_mfma_f32_16x16x32_bf16(af[i], bfr[j], acc[i][j], 0, 0, 0);
    }

    const int c0 = (bn >> 7) * 64 + wc * 32 + lrow;
    const int c1 = c0 + 16;
    const float bu0 = bias[bn + wc * 64 + lrow];
    const float bv0 = bias[bn + wc * 64 + 16 + lrow];
    const float bu1 = bias[bn + wc * 64 + 32 + lrow];
    const float bv1 = bias[bn + wc * 64 + 48 + lrow];
#pragma unroll
    for (int i = 0; i < 4; i++) {
#pragma unroll
        for (int r = 0; r < 4; r++) {
            size_t row = (size_t)(bm + wr * 64 + i * 16 + quad * 4 + r);
            float o0 = sigmoidf_(acc[i][0][r] + bu0) * (acc[i][1][r] + bv0);
            float o1 = sigmoidf_(acc[i][2][r] + bu1) * (acc[i][3][r] + bv1);
            if (rout) { rout[row * 128 + c0] = o0; rout[row * 128 + c1] = o1; }
            if (rb)   { rb[row * 128 + c0] = f2bu(o0); rb[row * 128 + c1] = f2bu(o1); }
        }
    }
}

// ================= small fp32 GEMM (stage-3 MLP only) =================
__global__ __launch_bounds__(256) void gemm_kernel(
    const float* __restrict__ A, int lda,
    const float* __restrict__ B, int ldb,
    const float* __restrict__ bias,
    float* __restrict__ C, int ldc,
    int K, int act)
{
    __shared__ float As[32][68];
    __shared__ float Bs[32][68];
    const int tid = threadIdx.x;
    const int bm = blockIdx.x * 64;
    const int bn = blockIdx.y * 64;
    const int tm = (tid & 15) * 4;
    const int tn = (tid >> 4) * 4;
    float acc[4][4] = {};

    for (int k0 = 0; k0 < K; k0 += 32) {
#pragma unroll
        for (int p = 0; p < 2; p++) {
            int lin = p * 256 + tid;
            int ar = lin >> 3;
            int ac = (lin & 7) << 2;
            float4 av = *(const float4*)(A + (size_t)(bm + ar) * lda + (k0 + ac));
            As[ac + 0][ar] = av.x;
            As[ac + 1][ar] = av.y;
            As[ac + 2][ar] = av.z;
            As[ac + 3][ar] = av.w;
            int br = lin >> 4;
            int bc = (lin & 15) << 2;
            *(float4*)&Bs[br][bc] = *(const float4*)(B + (size_t)(k0 + br) * ldb + (bn + bc));
        }
        __syncthreads();
#pragma unroll
        for (int k = 0; k < 32; k++) {
            float4 a4 = *(const float4*)&As[k][tm];
            float4 b4 = *(const float4*)&Bs[k][tn];
            float av[4] = {a4.x, a4.y, a4.z, a4.w};
            float bv[4] = {b4.x, b4.y, b4.z, b4.w};
#pragma unroll
            for (int i = 0; i < 4; i++)
#pragma unroll
                for (int j = 0; j < 4; j++)
                    acc[i][j] += av[i] * bv[j];
        }
        __syncthreads();
    }
#pragma unroll
    for (int i = 0; i < 4; i++) {
        size_t row = (size_t)(bm + tm + i);
#pragma unroll
        for (int j = 0; j < 4; j++) {
            int col = bn + tn + j;
            float val = acc[i][j] + (bias ? bias[col] : 0.f);
            if (act == 1) val = fmaxf(val, 0.f);
            C[row * ldc + col] = val;
        }
    }
}

// ================= weight prep =================
// Bfrag[(((et*4+ch)*2+wc)*4 + j)][lane][m] = W[et][k][c], k=ch*32+quad*8+m, c=wc*64+j*16+lrow
__global__ void prep_bfrag_kernel(const float* __restrict__ W, __hip_bfloat16* __restrict__ Bf,
                                  int net)
{
    int idx = blockIdx.x * blockDim.x + threadIdx.x;   // net*16384
    int m = idx & 7;
    int lane = (idx >> 3) & 63;
    int f = idx >> 9;
    int j = f & 3; f >>= 2;
    int wc = f & 1; f >>= 1;
    int ch = f & 3;
    int et = f >> 2;
    int quad = lane >> 4, lrow = lane & 15;
    int k = ch * 32 + quad * 8 + m;
    int c = wc * 64 + j * 16 + lrow;
    Bf[idx] = __float2bfloat16(W[et * 16384 + k * 128 + c]);
}

// GRU fused weights, output-col permuted: p -> gate g=(p>>4)&3, ch c=(p>>7)*32+((p>>6)&1)*16+(p&15)
__global__ void prep_gru_kernel(const float* __restrict__ wih, const float* __restrict__ whh,
                                const float* __restrict__ bih, const float* __restrict__ bhh,
                                const float* __restrict__ b, int net,
                                __hip_bfloat16* __restrict__ Bt, float* __restrict__ bias)
{
    int idx = blockIdx.x * blockDim.x + threadIdx.x;   // 512*288
    int p = idx / 288;
    int k = idx - p * 288;
    int g = (p >> 4) & 3;
    int c = (p >> 7) * 32 + ((p >> 6) & 1) * 16 + (p & 15);
    float val = 0.f;
    if (k < 128) {                                     // from a
        if (g == 0)      val = wih[k * 384 + c];
        else if (g == 1) val = wih[k * 384 + 128 + c];
        else if (g == 2) val = wih[k * 384 + 256 + c];
    } else if (k < 256) {                              // from h
        int kk = k - 128;
        if (g == 0)      val = whh[kk * 384 + c];
        else if (g == 1) val = whh[kk * 384 + 128 + c];
        else if (g == 3) val = whh[kk * 384 + 256 + c];
    } else {                                           // cnt cols: b @ wih
        int j = k - 256;
        if (j < net && g < 3) {
            int col = g * 128 + c;
            float s = 0.f;
            for (int kk = 0; kk < 128; kk++) s += b[j * 128 + kk] * wih[kk * 384 + col];
            val = s;
        }
    }
    Bt[idx] = __float2bfloat16(val);
    if (k == 0) {
        float bv;
        if (g == 0)      bv = bih[c] + bhh[c];
        else if (g == 1) bv = bih[128 + c] + bhh[128 + c];
        else if (g == 2) bv = bih[256 + c];
        else             bv = bhh[256 + c];
        bias[p] = bv;
    }
}

// Readout weights [256][288]: p -> side s=j&1 (0=u/iw,1=v/jw), ch = blk*64+wc*32+(j>>1)*16+t
__global__ void prep_ro_kernel(const float* __restrict__ iw, const float* __restrict__ jw,
                               const float* __restrict__ ib, const float* __restrict__ jb,
                               int Fin, __hip_bfloat16* __restrict__ Bt,
                               float* __restrict__ bias)
{
    int idx = blockIdx.x * blockDim.x + threadIdx.x;   // 256*288
    int p = idx / 288;
    int k = idx - p * 288;
    int j = (p >> 4) & 3;
    int s = j & 1;
    int c = ((p >> 7) & 1) * 64 + ((p >> 6) & 1) * 32 + (j >> 1) * 16 + (p & 15);
    float val = 0.f;
    if (k < 128) {
        val = s ? jw[k * 128 + c] : iw[k * 128 + c];
    } else if (k >= 160) {
        int kf = k - 160;
        if (kf < Fin && s == 0) val = iw[(128 + kf) * 128 + c];
    }
    Bt[idx] = __float2bfloat16(val);
    if (k == 0) bias[p] = s ? jb[c] : ib[c];
}

// ================= merged CSR build =================
__global__ void hist2_kernel(const int* __restrict__ bd, const int* __restrict__ be,
                             const int* __restrict__ kd, const int* __restrict__ ke,
                             int* __restrict__ counts)
{
    int e = blockIdx.x * blockDim.x + threadIdx.x;
    if (e >= E_TOT) return;
    if (e < E_BI) atomicAdd(&counts[bd[e] * 5 + be[e]], 1);
    else { int i = e - E_BI; atomicAdd(&counts[KN_BI + kd[i] * 9 + ke[i]], 1); }
}

__global__ void scan1_kernel(const int* __restrict__ counts, int* __restrict__ local_ex,
                             int* __restrict__ partial)
{
    __shared__ int s[256];
    int t = threadIdx.x;
    int i = blockIdx.x * 256 + t;
    int v = counts[i];
    s[t] = v;
    __syncthreads();
    for (int off = 1; off < 256; off <<= 1) {
        int x = 0;
        if (t >= off) x = s[t - off];
        __syncthreads();
        if (t >= off) s[t] += x;
        __syncthreads();
    }
    local_ex[i] = s[t] - v;
    if (t == 255) partial[blockIdx.x] = s[255];
}

__global__ void scan2b_kernel(int* __restrict__ partial, int nb, int* __restrict__ last, int E)
{
    __shared__ int s[256];
    int t = threadIdx.x;
    int loc[11];
    int sum = 0;
#pragma unroll
    for (int q = 0; q < 11; q++) {
        int idx = t * 11 + q;
        int v = (idx < nb) ? partial[idx] : 0;
        loc[q] = sum; sum += v;
    }
    s[t] = sum;
    __syncthreads();
    for (int off = 1; off < 256; off <<= 1) {
        int x = 0;
        if (t >= off) x = s[t - off];
        __syncthreads();
        if (t >= off) s[t] += x;
        __syncthreads();
    }
    int excl = s[t] - sum;
#pragma unroll
    for (int q = 0; q < 11; q++) {
        int idx = t * 11 + q;
        if (idx < nb) partial[idx] = excl + loc[q];
    }
    if (t == 0) *last = E;
}

__global__ void scan3c_kernel(int* __restrict__ indptr, const int* __restrict__ partial,
                              int* __restrict__ cursor)
{
    int i = blockIdx.x * 256 + threadIdx.x;
    int v = indptr[i] + partial[blockIdx.x];
    indptr[i] = v;
    cursor[i] = v;
}

__global__ void fill2_kernel(const int* __restrict__ bs, const int* __restrict__ bd,
                             const int* __restrict__ be,
                             const int* __restrict__ ks, const int* __restrict__ kd,
                             const int* __restrict__ ke,
                             int* __restrict__ cursor, int* __restrict__ elist)
{
    int e = blockIdx.x * blockDim.x + threadIdx.x;
    if (e >= E_TOT) return;
    if (e < E_BI) {
        int pos = atomicAdd(&cursor[bd[e] * 5 + be[e]], 1);
        elist[pos] = bs[e];
    } else {
        int i = e - E_BI;
        int pos = atomicAdd(&cursor[KN_BI + kd[i] * 9 + ke[i]], 1);
        elist[pos] = ks[i];
    }
}

// cnt columns into BOTH ah buffers
__global__ void cnt_kernel(const int* __restrict__ indptr, int net,
                           ushort* __restrict__ ahA, ushort* __restrict__ ahB)
{
    int idx = blockIdx.x * blockDim.x + threadIdx.x;   // N*32
    int v = idx >> 5;
    int j = idx & 31;
    float cv = 0.f;
    if (j < net) cv = (float)(indptr[v * net + j + 1] - indptr[v * net + j]);
    ushort u = f2bu(cv);
    ahA[(size_t)v * AH_S + 256 + j] = u;
    ahB[(size_t)v * AH_S + 256 + j] = u;
}

// ================= elementwise =================
// feat -> h fp32 + ahA h-cols + feat-cols (both buffers) + hb
__global__ void pad_kernel(const float* __restrict__ fsrc, const ushort* __restrict__ bsrc,
                           float* __restrict__ h, uint* __restrict__ ahA,
                           uint* __restrict__ ahB, uint* __restrict__ hb, int Fin)
{
    int idx = blockIdx.x * blockDim.x + threadIdx.x;   // N*32
    int v = idx >> 5;
    int c = (idx & 31) * 4;
    float4 val = make_float4(0.f, 0.f, 0.f, 0.f);
    if (bsrc) {
        uint2 u = *(const uint2*)(bsrc + (size_t)v * Fin + c);
        val.x = blo(u.x); val.y = bhi(u.x);
        val.z = blo(u.y); val.w = bhi(u.y);
    } else if (c < Fin) {
        val = *(const float4*)(fsrc + (size_t)v * Fin + c);
    }
    *(float4*)(h + (size_t)v * 128 + c) = val;
    uint2 pk;
    pk.x = (uint)f2bu(val.x) | ((uint)f2bu(val.y) << 16);
    pk.y = (uint)f2bu(val.z) | ((uint)f2bu(val.w) << 16);
    *(uint2*)(ahA + (size_t)v * AH_U + 64 + c / 2) = pk;    // h cols (step-0 input)
    *(uint2*)(ahA + (size_t)v * AH_U + 144 + c / 2) = pk;   // feat cols (readout input)
    *(uint2*)(ahB + (size_t)v * AH_U + 144 + c / 2) = pk;
    *(uint2*)(hb + (size_t)v * 64 + c / 2) = pk;
}

__global__ void pool_kernel(const float* __restrict__ r2, float* __restrict__ pooled)
{
    int s = blockIdx.x;
    int c = threadIdx.x;
    const float* base = r2 + (size_t)(2 * s) * PER * 128;
    float acc = 0.f;
    for (int i = 0; i < PER; i++) acc += base[(size_t)i * 128 + c];
    pooled[s * 128 + c] = acc;
}

__global__ void out_kernel(const float* __restrict__ x2, const float* __restrict__ wo,
                           const float* __restrict__ bo, float* __restrict__ out)
{
    int row = blockIdx.x;
    int t = threadIdx.x;
    float s = x2[row * 128 + t] * wo[t] + x2[row * 128 + 64 + t] * wo[64 + t];
#pragma unroll
    for (int off = 32; off; off >>= 1) s += __shfl_down(s, off);
    if (t == 0) out[row] = s + bo[0];
}

struct GGParams {
    const float *W, *b, *wih, *whh, *bih, *bhh, *iw, *ib, *jw, *jb;
};

struct WsPtrs {
    float* h;
    __hip_bfloat16 *ah0, *ah1;   // [N,416] bf16 ping-pong
    float* G;                    // 2*n128: rout2 | hb
    uint* hb;
    __hip_bfloat16* r1b;
    __hip_bfloat16 *bfragB, *gruB, *roB;
    float *gruBias, *roBias;
    int *indptr, *cursor, *partial, *elist;
    float *pooled, *x1, *x2;
};

template<int NET>
static void run_stage(hipStream_t st, const float* featF, const __hip_bfloat16* featB, int Fin,
                      const GGParams& p, const WsPtrs& w, const int* indptr_slice,
                      float* rout, __hip_bfloat16* rout_b)
{
    const int N = N_NODES;
    ushort* ahA = (ushort*)w.ah0;
    ushort* ahB = (ushort*)w.ah1;
    ushort* hbS = (ushort*)w.hb;

    prep_bfrag_kernel<<<(NET * 16384) / 256, 256, 0, st>>>(p.W, w.bfragB, NET);
    prep_gru_kernel<<<(512 * 288) / 256, 256, 0, st>>>(p.wih, p.whh, p.bih, p.bhh, p.b, NET,
                                                       w.gruB, w.gruBias);
    prep_ro_kernel<<<(256 * 288) / 256, 256, 0, st>>>(p.iw, p.jw, p.ib, p.jb, Fin,
                                                      w.roB, w.roBias);

    cnt_kernel<<<(N * 32) / 256, 256, 0, st>>>(indptr_slice, NET, ahA, ahB);
    pad_kernel<<<(N * 32) / 256, 256, 0, st>>>(featF, (const ushort*)featB, w.h,
                                               (uint*)ahA, (uint*)ahB, w.hb, Fin);

    ushort* ahIn = ahA;
    ushort* ahOut = ahB;
    for (int step = 0; step < 2; step++) {
        msg_kernel<NET><<<N / 32, 256, 0, st>>>(w.hb, indptr_slice, w.elist,
                                                (ushort*)w.bfragB, ahIn);
        dim3 g(N / 128, 4);
        gru_gemm_kernel<<<g, 256, 0, st>>>(ahIn, (ushort*)w.gruB, w.gruBias, w.h, ahOut, hbS);
        ushort* t = ahIn; ahIn = ahOut; ahOut = t;
    }
    // after 2 steps, latest h lives in ahA (== ahIn) together with cnt|feat
    dim3 gr(N / 128, 2);
    ro_gemm_kernel<<<gr, 256, 0, st>>>(ahIn + 128, (ushort*)w.roB, w.roBias,
                                       rout, (ushort*)rout_b);
}

extern "C" void kernel_launch(void* const* d_in, const int* in_sizes, int n_in,
                              void* d_out, int out_size, void* d_ws, size_t ws_size,
                              hipStream_t stream)
{
    const float* feat    = (const float*)d_in[0];
    const int*   bi_src  = (const int*)d_in[1];
    const int*   bi_dst  = (const int*)d_in[2];
    const int*   bi_et   = (const int*)d_in[3];
    const int*   knn_src = (const int*)d_in[4];
    const int*   knn_dst = (const int*)d_in[5];
    const int*   knn_et  = (const int*)d_in[6];

    GGParams s1 { (const float*)d_in[8],  (const float*)d_in[9],  (const float*)d_in[10],
                  (const float*)d_in[11], (const float*)d_in[12], (const float*)d_in[13],
                  (const float*)d_in[14], (const float*)d_in[15], (const float*)d_in[16],
                  (const float*)d_in[17] };
    GGParams s2 { (const float*)d_in[18], (const float*)d_in[19], (const float*)d_in[20],
                  (const float*)d_in[21], (const float*)d_in[22], (const float*)d_in[23],
                  (const float*)d_in[24], (const float*)d_in[25], (const float*)d_in[26],
                  (const float*)d_in[27] };
    const float* w0 = (const float*)d_in[28];
    const float* b0 = (const float*)d_in[29];
    const float* w1 = (const float*)d_in[30];
    const float* b1 = (const float*)d_in[31];
    const float* wo = (const float*)d_in[32];
    const float* bo = (const float*)d_in[33];

    const int N = N_NODES;
    const size_t n128 = (size_t)N * 128;

    float* ws = (float*)d_ws;
    WsPtrs w;
    size_t off = 0;
    w.h      = ws + off;                       off += n128;
    w.ah0    = (__hip_bfloat16*)(ws + off);    off += (size_t)N * 208;
    w.ah1    = (__hip_bfloat16*)(ws + off);    off += (size_t)N * 208;
    w.G      = ws + off;                       off += 2 * n128;
    w.hb     = (uint*)(w.G + n128);            // second half of G
    w.r1b    = (__hip_bfloat16*)(ws + off);    off += n128 / 2;
    w.bfragB = (__hip_bfloat16*)(ws + off);    off += 9 * 16384 / 2;
    w.gruB   = (__hip_bfloat16*)(ws + off);    off += 512 * 288 / 2;
    w.roB    = (__hip_bfloat16*)(ws + off);    off += 256 * 288 / 2;
    w.gruBias = ws + off;                      off += 512;
    w.roBias  = ws + off;                      off += 256;
    w.indptr  = (int*)(ws + off);              off += KN_TOT + 8;
    w.cursor  = (int*)(ws + off);              off += KN_TOT;
    w.partial = (int*)(ws + off);              off += 4096;
    w.elist   = (int*)(ws + off);              off += E_TOT;
    w.pooled  = ws + off;                      off += 64 * 128;
    w.x1      = ws + off;                      off += 64 * 256;
    w.x2      = ws + off;                      off += 64 * 128;

    // ---- merged CSR build ----
    hipMemsetAsync(w.cursor, 0, KN_TOT * sizeof(int), stream);
    hist2_kernel<<<(E_TOT + 255) / 256, 256, 0, stream>>>(bi_dst, bi_et, knn_dst, knn_et, w.cursor);
    scan1_kernel<<<KN_TOT / 256, 256, 0, stream>>>(w.cursor, w.indptr, w.partial);
    scan2b_kernel<<<1, 256, 0, stream>>>(w.partial, KN_TOT / 256, w.indptr + KN_TOT, E_TOT);
    scan3c_kernel<<<KN_TOT / 256, 256, 0, stream>>>(w.indptr, w.partial, w.cursor);
    fill2_kernel<<<(E_TOT + 255) / 256, 256, 0, stream>>>(bi_src, bi_dst, bi_et,
                                                          knn_src, knn_dst, knn_et,
                                                          w.cursor, w.elist);

    // Stage 1: bond graph (5 etypes), Fin=64
    run_stage<5>(stream, feat, nullptr, 64, s1, w, w.indptr, nullptr, w.r1b);
    // Stage 2: knn graph (9 etypes), feat = stage-1 readout (bf16)
    float* rout2 = w.G;
    run_stage<9>(stream, nullptr, w.r1b, 128, s2, w, w.indptr + KN_BI, rout2, nullptr);

    // Stage 3: ligand pooling + MLP
    pool_kernel<<<64, 128, 0, stream>>>(rout2, w.pooled);
    {
        dim3 g1(1, 4);
        gemm_kernel<<<g1, 256, 0, stream>>>(w.pooled, 128, w0, 256, b0, w.x1, 256, 128, 1);
        dim3 g2(1, 2);
        gemm_kernel<<<g2, 256, 0, stream>>>(w.x1, 256, w1, 128, b1, w.x2, 128, 256, 1);
    }
    out_kernel<<<64, 64, 0, stream>>>(w.x2, wo, bo, (float*)d_out);
}